// Round 3
// baseline (57657.050 us; speedup 1.0000x reference)
//
#include <hip/hip_runtime.h>
#include <cstddef>

#define HID   512
#define G4    2048   // 4*HID
#define NB    32     // batch
#define SEQL  1024
#define INPD  512
#define NBLK  128    // persistent blocks: block j owns hidden units [4j, 4j+4)
#define TPB   512

__device__ __forceinline__ float sigm(float x) {
    return 1.0f / (1.0f + __expf(-x));
}
__device__ __forceinline__ float tanh_fast(float x) {
    float e = __expf(-2.0f * fabsf(x));
    float t = (1.0f - e) / (1.0f + e);
    return copysignf(t, x);
}

// x_proj chunk GEMM: xbuf[m][n] = sum_k inputs[row(m)][k] * w_ih[n][k] + bih[n] + bhh[n]
// m enumerates (b, tloc) b-major; M = NB*SC, N = 2048, K = 512.
__global__ __launch_bounds__(256) void xproj_gemm(const float* __restrict__ x,
                                                  const float* __restrict__ wih,
                                                  const float* __restrict__ bih,
                                                  const float* __restrict__ bhh,
                                                  float* __restrict__ xbuf,
                                                  int chunk, int SC) {
    __shared__ float As[16][68];  // [k][m_local]
    __shared__ float Bs[16][68];  // [k][n_local]
    const int m0 = blockIdx.x * 64;
    const int n0 = blockIdx.y * 64;
    const int tid = threadIdx.x;
    const int tx = tid % 16;       // n-dir
    const int ty = tid / 16;       // m-dir
    const int lr  = tid / 4;       // load row 0..63
    const int lc4 = tid % 4;       // which float4 of 16 k's

    float acc[4][4] = {};

    const int m = m0 + lr;
    const int b  = m / SC;
    const int tl = m % SC;
    const float* arow_base = x + ((size_t)b * SEQL + (size_t)chunk * SC + tl) * INPD + lc4 * 4;
    const float* brow_base = wih + (size_t)(n0 + lr) * INPD + lc4 * 4;

    for (int k0 = 0; k0 < 512; k0 += 16) {
        float4 a4 = *(const float4*)(arow_base + k0);
        float4 b4 = *(const float4*)(brow_base + k0);
        As[lc4 * 4 + 0][lr] = a4.x;
        As[lc4 * 4 + 1][lr] = a4.y;
        As[lc4 * 4 + 2][lr] = a4.z;
        As[lc4 * 4 + 3][lr] = a4.w;
        Bs[lc4 * 4 + 0][lr] = b4.x;
        Bs[lc4 * 4 + 1][lr] = b4.y;
        Bs[lc4 * 4 + 2][lr] = b4.z;
        Bs[lc4 * 4 + 3][lr] = b4.w;
        __syncthreads();
        #pragma unroll
        for (int kk = 0; kk < 16; ++kk) {
            float4 av = *(const float4*)&As[kk][ty * 4];
            float4 bv = *(const float4*)&Bs[kk][tx * 4];
            float a[4] = {av.x, av.y, av.z, av.w};
            float bb[4] = {bv.x, bv.y, bv.z, bv.w};
            #pragma unroll
            for (int i = 0; i < 4; ++i)
                #pragma unroll
                for (int j = 0; j < 4; ++j)
                    acc[i][j] = fmaf(a[i], bb[j], acc[i][j]);
        }
        __syncthreads();
    }

    #pragma unroll
    for (int i = 0; i < 4; ++i) {
        int mo = m0 + ty * 4 + i;
        float* orow = xbuf + (size_t)mo * G4;
        #pragma unroll
        for (int j = 0; j < 4; ++j) {
            int n = n0 + tx * 4 + j;
            orow[n] = acc[i][j] + bih[n] + bhh[n];
        }
    }
}

// Persistent recurrence kernel. 128 blocks x 512 threads; block j owns hidden
// units [4j, 4j+4) => 16 gate rows (i,f,g,o x 4 units) for ALL 32 batches
// (16 rows x 32 batches = 512 dot products = 1 per thread).
// W slice lives in LDS for the whole chunk. h is exchanged through global
// memory (double-buffered) with a flag-based all-block barrier per step.
__global__ __launch_bounds__(512)
void lstm_persist(const float* __restrict__ whh,   // [2048][512]
                  const float* __restrict__ xbuf,  // [NB*SC][G4]
                  const float* __restrict__ h0,    // [NB][HID] (step 0 only)
                  const float* __restrict__ c0,    // [NB][HID] (chunk 0 only)
                  float* __restrict__ hbuf,        // [2][NB][HID]
                  float* __restrict__ cstate,      // [NB][HID]
                  float* __restrict__ out,         // [NB][SEQL][HID]
                  int* __restrict__ flags,         // [NBLK], monotonic
                  int step_base, int SC) {
    __shared__ float Wl[16][516];   // 16 gate rows, padded
    __shared__ float gl[32][17];    // gate exchange [b][n], padded

    const int j  = blockIdx.x;
    const int t  = threadIdx.x;
    const int u0 = 4 * j;            // j < 128 -> u0 <= 508

    // ---- load W slice into LDS (row n = type*4+uu  ->  whh row type*512+u0+uu)
    {
        int n    = t >> 5;           // 0..15
        int type = n >> 2, uu = n & 3;
        int k0   = (t & 31) * 16;
        const float4* s4 = (const float4*)(whh + (size_t)(type * HID + u0 + uu) * INPD + k0);
        float4* d4 = (float4*)&Wl[n][k0];
        #pragma unroll
        for (int q = 0; q < 4; ++q) d4[q] = s4[q];
    }

    // ---- cell state: threads t<128 own (u = t>>5, b = t&31)
    float c = 0.0f;
    if (t < 128) {
        int u = t >> 5, bb = t & 31;
        c = (step_base == 0 ? c0 : cstate)[bb * HID + u0 + u];
    }
    __syncthreads();

    const int n    = t & 15;      // gate row within block
    const int b    = t >> 4;      // batch
    const int type = n >> 2, uu = n & 3;
    const int grow = type * HID + u0 + uu;   // global gate column in xbuf (<= 2047)

    for (int s = 0; s < SC; ++s) {
        const int gstep = step_base + s;
        const float* hsrc = (gstep == 0) ? h0
                          : hbuf + (size_t)(gstep & 1) * NB * HID;

        // ---- phase A: gate dot product (W from LDS, h from global/L2)
        const float* hb = hsrc + b * HID;
        const float* wr = &Wl[n][0];
        float xg = xbuf[((size_t)b * SC + s) * G4 + grow];
        float4 a4 = {0.f, 0.f, 0.f, 0.f};
        #pragma unroll 8
        for (int k = 0; k < HID; k += 4) {
            float4 h4 = *(const float4*)(hb + k);
            float4 w4 = *(const float4*)(wr + k);
            a4.x = fmaf(w4.x, h4.x, a4.x);
            a4.y = fmaf(w4.y, h4.y, a4.y);
            a4.z = fmaf(w4.z, h4.z, a4.z);
            a4.w = fmaf(w4.w, h4.w, a4.w);
        }
        gl[b][n] = (a4.x + a4.y) + (a4.z + a4.w) + xg;
        __syncthreads();

        // ---- phase B: cell update for this block's 4 units x 32 batches
        if (t < 128) {
            int u = t >> 5, bb = t & 31;
            float i_t = sigm(gl[bb][0 + u]);
            float f_t = sigm(gl[bb][4 + u]);
            float g_t = tanh_fast(gl[bb][8 + u]);
            float o_t = sigm(gl[bb][12 + u]);
            c = fmaf(f_t, c, i_t * g_t);
            float hnew = o_t * tanh_fast(c);
            int col = u0 + u;
            hbuf[(size_t)((gstep + 1) & 1) * NB * HID + bb * HID + col] = hnew;
            out[((size_t)bb * SEQL + gstep) * HID + col] = hnew;
        }
        __threadfence();        // release h writes device-wide
        __syncthreads();        // whole block done before flagging

        if (t == 0)
            __hip_atomic_store(&flags[j], gstep + 1,
                               __ATOMIC_RELEASE, __HIP_MEMORY_SCOPE_AGENT);

        // ---- all-block barrier: poll NBLK flags
        const int target = gstep + 1;
        for (;;) {
            int f = target;
            if (t < NBLK)
                f = __hip_atomic_load(&flags[t],
                                      __ATOMIC_ACQUIRE, __HIP_MEMORY_SCOPE_AGENT);
            if (__syncthreads_and(f >= target)) break;
            __builtin_amdgcn_s_sleep(2);
        }
        __threadfence();        // acquire: invalidate stale h lines
        __syncthreads();        // keep gl reuse ordered vs next phase A
    }

    if (t < 128) {
        int u = t >> 5, bb = t & 31;
        cstate[bb * HID + u0 + u] = c;
    }
}

__global__ __launch_bounds__(256) void finalize(const float* __restrict__ hfin,
                                                const float* __restrict__ cs,
                                                float* __restrict__ out) {
    int i = blockIdx.x * blockDim.x + threadIdx.x;
    size_t base = (size_t)NB * SEQL * HID;
    if (i < NB * HID) {
        out[base + i] = hfin[i];
        out[base + NB * HID + i] = cs[i];
    }
}

extern "C" void kernel_launch(void* const* d_in, const int* in_sizes, int n_in,
                              void* d_out, int out_size, void* d_ws, size_t ws_size,
                              hipStream_t stream) {
    const float* x   = (const float*)d_in[0];
    const float* h0  = (const float*)d_in[1];
    const float* c0  = (const float*)d_in[2];
    const float* wih = (const float*)d_in[3];
    const float* whh = (const float*)d_in[4];
    const float* bih = (const float*)d_in[5];
    const float* bhh = (const float*)d_in[6];
    float* out = (float*)d_out;

    char* ws = (char*)d_ws;
    int*   flags  = (int*)ws;                        // 4 KB reserved
    float* hbuf   = (float*)(ws + 4096);             // 2 * 64 KB
    float* cstate = hbuf + 2 * NB * HID;             // 64 KB
    float* xbuf   = cstate + NB * HID;

    size_t fixed = 4096 + (size_t)3 * NB * HID * sizeof(float);
    int SC = SEQL;                                    // prefer one persistent launch
    while (SC > 64 && fixed + (size_t)NB * SC * G4 * sizeof(float) > ws_size) SC >>= 1;

    hipMemsetAsync(flags, 0, NBLK * sizeof(int), stream);

    int nchunks = SEQL / SC;
    for (int ch = 0; ch < nchunks; ++ch) {
        dim3 g(NB * SC / 64, G4 / 64);
        xproj_gemm<<<g, 256, 0, stream>>>(x, wih, bih, bhh, xbuf, ch, SC);
        lstm_persist<<<NBLK, TPB, 0, stream>>>(whh, xbuf, h0, c0, hbuf, cstate, out,
                                               flags, ch * SC, SC);
    }

    // total steps = 1024 (even) -> final h parity is buffer 0
    finalize<<<(NB * HID + 255) / 256, 256, 0, stream>>>(hbuf, cstate, out);
}

// Round 4
// 12615.201 us; speedup vs baseline: 4.5704x; 4.5704x over previous
//
#include <hip/hip_runtime.h>
#include <cstddef>

#define HID   512
#define G4    2048   // 4*HID
#define NB    32     // batch
#define SEQL  1024
#define INPD  512
#define NBLK  128    // persistent blocks: block j owns hidden units [4j, 4j+4)
#define TPB   512

__device__ __forceinline__ float sigm(float x) {
    return 1.0f / (1.0f + __expf(-x));
}
__device__ __forceinline__ float tanh_fast(float x) {
    float e = __expf(-2.0f * fabsf(x));
    float t = (1.0f - e) / (1.0f + e);
    return copysignf(t, x);
}

// x_proj chunk GEMM: xbuf[m][n] = sum_k inputs[row(m)][k] * w_ih[n][k] + bih[n] + bhh[n]
__global__ __launch_bounds__(256) void xproj_gemm(const float* __restrict__ x,
                                                  const float* __restrict__ wih,
                                                  const float* __restrict__ bih,
                                                  const float* __restrict__ bhh,
                                                  float* __restrict__ xbuf,
                                                  int chunk, int SC) {
    __shared__ float As[16][68];  // [k][m_local]
    __shared__ float Bs[16][68];  // [k][n_local]
    const int m0 = blockIdx.x * 64;
    const int n0 = blockIdx.y * 64;
    const int tid = threadIdx.x;
    const int tx = tid % 16;       // n-dir
    const int ty = tid / 16;       // m-dir
    const int lr  = tid / 4;       // load row 0..63
    const int lc4 = tid % 4;       // which float4 of 16 k's

    float acc[4][4] = {};

    const int m = m0 + lr;
    const int b  = m / SC;
    const int tl = m % SC;
    const float* arow_base = x + ((size_t)b * SEQL + (size_t)chunk * SC + tl) * INPD + lc4 * 4;
    const float* brow_base = wih + (size_t)(n0 + lr) * INPD + lc4 * 4;

    for (int k0 = 0; k0 < 512; k0 += 16) {
        float4 a4 = *(const float4*)(arow_base + k0);
        float4 b4 = *(const float4*)(brow_base + k0);
        As[lc4 * 4 + 0][lr] = a4.x;
        As[lc4 * 4 + 1][lr] = a4.y;
        As[lc4 * 4 + 2][lr] = a4.z;
        As[lc4 * 4 + 3][lr] = a4.w;
        Bs[lc4 * 4 + 0][lr] = b4.x;
        Bs[lc4 * 4 + 1][lr] = b4.y;
        Bs[lc4 * 4 + 2][lr] = b4.z;
        Bs[lc4 * 4 + 3][lr] = b4.w;
        __syncthreads();
        #pragma unroll
        for (int kk = 0; kk < 16; ++kk) {
            float4 av = *(const float4*)&As[kk][ty * 4];
            float4 bv = *(const float4*)&Bs[kk][tx * 4];
            float a[4] = {av.x, av.y, av.z, av.w};
            float bb[4] = {bv.x, bv.y, bv.z, bv.w};
            #pragma unroll
            for (int i = 0; i < 4; ++i)
                #pragma unroll
                for (int j = 0; j < 4; ++j)
                    acc[i][j] = fmaf(a[i], bb[j], acc[i][j]);
        }
        __syncthreads();
    }

    #pragma unroll
    for (int i = 0; i < 4; ++i) {
        int mo = m0 + ty * 4 + i;
        float* orow = xbuf + (size_t)mo * G4;
        #pragma unroll
        for (int j = 0; j < 4; ++j) {
            int n = n0 + tx * 4 + j;
            orow[n] = acc[i][j] + bih[n] + bhh[n];
        }
    }
}

// Persistent recurrence. 128 blocks x 512 threads; block j owns hidden units
// [4j,4j+4) => 16 gate rows x 32 batches = 512 dots (1/thread).
// Fence-free cross-block exchange: all h/sync traffic uses RELAXED agent-scope
// atomics (performed at LLC, bypassing the non-coherent per-XCD L2). No
// __threadfence => no buffer_wbl2/buffer_inv per step.
__global__ __launch_bounds__(512)
void lstm_persist(const float* __restrict__ whh,   // [2048][512]
                  const float* __restrict__ xbuf,  // [NB*SC][G4]
                  const float* __restrict__ h0,
                  const float* __restrict__ c0,
                  float* __restrict__ hbuf,        // [2][NB][HID]
                  float* __restrict__ cstate,      // [NB][HID]
                  float* __restrict__ out,         // [NB][SEQL][HID]
                  int* __restrict__ sync,          // [0]=cnt, [64]=go
                  int step_base, int SC) {
    __shared__ float Wl[16][516];      // W slice, padded: n -> bank quad 4n%32
    __shared__ float h_lds[32][516];   // staged h, padded: b -> bank quad 4b%32
    __shared__ float gl[32][17];       // gate exchange

    const int j  = blockIdx.x;
    const int t  = threadIdx.x;
    const int u0 = 4 * j;

    // ---- load W slice into LDS
    {
        int n    = t >> 5;           // 0..15
        int type = n >> 2, uu = n & 3;
        int k0   = (t & 31) * 16;
        const float4* s4 = (const float4*)(whh + (size_t)(type * HID + u0 + uu) * INPD + k0);
        float4* d4 = (float4*)&Wl[n][k0];
        #pragma unroll
        for (int q = 0; q < 4; ++q) d4[q] = s4[q];
    }

    float c = 0.0f;
    if (t < 128) {
        int u = t >> 5, bb = t & 31;
        c = (step_base == 0 ? c0 : cstate)[bb * HID + u0 + u];
    }

    const int n    = t & 15;      // gate row within block
    const int b    = t >> 4;      // batch
    const int type = n >> 2, uu = n & 3;
    const int grow = type * HID + u0 + uu;

    int* cnt = sync;
    int* go  = sync + 64;

    for (int s = 0; s < SC; ++s) {
        const int g = step_base + s;

        // ---- stage h (64KB) into LDS via LLC-coherent 8B loads
        const float* hsrc = (g == 0) ? h0 : hbuf + (size_t)(g & 1) * NB * HID;
        const unsigned long long* hs8 = (const unsigned long long*)hsrc;
        #pragma unroll
        for (int q = 0; q < 16; ++q) {
            unsigned long long v = __hip_atomic_load(hs8 + q * 512 + t,
                                                     __ATOMIC_RELAXED,
                                                     __HIP_MEMORY_SCOPE_AGENT);
            int f2 = q * 512 + t;          // float2 index
            int bb = f2 >> 8, k2 = f2 & 255;
            float2 hv;
            __builtin_memcpy(&hv, &v, 8);
            *(float2*)&h_lds[bb][k2 * 2] = hv;
        }
        __syncthreads();

        // ---- phase A: gate dot (both operands in LDS, conflict-free)
        float xg = xbuf[((size_t)b * SC + s) * G4 + grow];
        const float* hb = &h_lds[b][0];
        const float* wr = &Wl[n][0];
        float4 a4 = {0.f, 0.f, 0.f, 0.f};
        #pragma unroll 8
        for (int k = 0; k < HID; k += 4) {
            float4 h4 = *(const float4*)(hb + k);
            float4 w4 = *(const float4*)(wr + k);
            a4.x = fmaf(w4.x, h4.x, a4.x);
            a4.y = fmaf(w4.y, h4.y, a4.y);
            a4.z = fmaf(w4.z, h4.z, a4.z);
            a4.w = fmaf(w4.w, h4.w, a4.w);
        }
        gl[b][n] = (a4.x + a4.y) + (a4.z + a4.w) + xg;
        __syncthreads();

        // ---- phase B: cell update (4 units x 32 batches)
        if (t < 128) {
            int u = t >> 5, bb = t & 31;
            float i_t = sigm(gl[bb][0 + u]);
            float f_t = sigm(gl[bb][4 + u]);
            float g_t = tanh_fast(gl[bb][8 + u]);
            float o_t = sigm(gl[bb][12 + u]);
            c = fmaf(f_t, c, i_t * g_t);
            float hnew = o_t * tanh_fast(c);
            int col = u0 + u;
            __hip_atomic_store(&hbuf[(size_t)((g + 1) & 1) * NB * HID + bb * HID + col],
                               hnew, __ATOMIC_RELAXED, __HIP_MEMORY_SCOPE_AGENT);
            out[((size_t)bb * SEQL + g) * HID + col] = hnew;
        }
        __syncthreads();   // each wave drains vmcnt before s_barrier => h stores acked at LLC

        // ---- arrive: single atomic counter; last arriver publishes go
        if (t == 0) {
            int old = __hip_atomic_fetch_add(cnt, 1, __ATOMIC_RELAXED,
                                             __HIP_MEMORY_SCOPE_AGENT);
            if (old == NBLK * (g + 1) - 1)
                __hip_atomic_store(go, g + 1, __ATOMIC_RELAXED,
                                   __HIP_MEMORY_SCOPE_AGENT);
        }
        // ---- wait: wave 0 polls the single go word
        if (t < 64) {
            while (__hip_atomic_load(go, __ATOMIC_RELAXED,
                                     __HIP_MEMORY_SCOPE_AGENT) < g + 1)
                __builtin_amdgcn_s_sleep(4);
        }
        __syncthreads();
    }

    if (t < 128) {
        int u = t >> 5, bb = t & 31;
        cstate[bb * HID + u0 + u] = c;
    }
}

__global__ __launch_bounds__(256) void finalize(const float* __restrict__ hfin,
                                                const float* __restrict__ cs,
                                                float* __restrict__ out) {
    int i = blockIdx.x * blockDim.x + threadIdx.x;
    size_t base = (size_t)NB * SEQL * HID;
    if (i < NB * HID) {
        out[base + i] = hfin[i];
        out[base + NB * HID + i] = cs[i];
    }
}

extern "C" void kernel_launch(void* const* d_in, const int* in_sizes, int n_in,
                              void* d_out, int out_size, void* d_ws, size_t ws_size,
                              hipStream_t stream) {
    const float* x   = (const float*)d_in[0];
    const float* h0  = (const float*)d_in[1];
    const float* c0  = (const float*)d_in[2];
    const float* wih = (const float*)d_in[3];
    const float* whh = (const float*)d_in[4];
    const float* bih = (const float*)d_in[5];
    const float* bhh = (const float*)d_in[6];
    float* out = (float*)d_out;

    char* ws = (char*)d_ws;
    int*   sync   = (int*)ws;                        // 4 KB reserved (cnt@0, go@64)
    float* hbuf   = (float*)(ws + 4096);             // 2 * 64 KB
    float* cstate = hbuf + 2 * NB * HID;             // 64 KB
    float* xbuf   = cstate + NB * HID;

    size_t fixed = 4096 + (size_t)3 * NB * HID * sizeof(float);
    int SC = SEQL;                                    // prefer one persistent launch
    while (SC > 64 && fixed + (size_t)NB * SC * G4 * sizeof(float) > ws_size) SC >>= 1;

    hipMemsetAsync(sync, 0, 4096, stream);

    int nchunks = SEQL / SC;
    for (int ch = 0; ch < nchunks; ++ch) {
        dim3 grd(NB * SC / 64, G4 / 64);
        xproj_gemm<<<grd, 256, 0, stream>>>(x, wih, bih, bhh, xbuf, ch, SC);
        lstm_persist<<<NBLK, TPB, 0, stream>>>(whh, xbuf, h0, c0, hbuf, cstate, out,
                                               sync, ch * SC, SC);
    }

    // total steps = 1024 (even) -> final h parity is buffer 0
    finalize<<<(NB * HID + 255) / 256, 256, 0, stream>>>(hbuf, cstate, out);
}